// Round 5
// baseline (503.302 us; speedup 1.0000x reference)
//
#include <hip/hip_runtime.h>
#include <math.h>

// Problem constants (from reference)
#define BATCH 1024
#define DIM   512
#define NCLS  100000
#define SCALE_S 64.0f
#define MARGIN  0.5f
#define EPS_REF 1e-7f
#define NBLK 782          // ceil(NCLS/128)
#define MBLK 8            // BATCH/128
#define BK   64           // K-slab per barrier iteration

typedef __attribute__((ext_vector_type(8))) short short8;
typedef __attribute__((ext_vector_type(4))) float floatx4;

// ---------- helpers ----------
__device__ __forceinline__ unsigned short f2bf(float f) {
    union { float f; unsigned u; } v; v.f = f;
    unsigned r = v.u + 0x7FFFu + ((v.u >> 16) & 1u);   // RNE to bf16
    return (unsigned short)(r >> 16);
}

// async global->LDS, 16B per lane; LDS dest = wave-uniform base + lane*16
__device__ __forceinline__ void gload_lds16(const void* g, void* l) {
    __builtin_amdgcn_global_load_lds(
        (const __attribute__((address_space(1))) void*)g,
        (__attribute__((address_space(3))) void*)l, 16, 0, 0);
}

// ---------- W fp32 -> bf16 (RTZ), pure streaming ----------
// 25000 blocks x 256 thr, 8 floats/thread (exact cover of 51.2M)
__global__ void k_wcvt(const float* __restrict__ W,
                       unsigned short* __restrict__ wbf) {
    const size_t i = ((size_t)blockIdx.x * 256 + threadIdx.x) * 8;
    const float4 lo = *(const float4*)(W + i);
    const float4 hi = *(const float4*)(W + i + 4);
    uint4 p;
    p.x = (__float_as_uint(lo.x) >> 16) | (__float_as_uint(lo.y) & 0xFFFF0000u);
    p.y = (__float_as_uint(lo.z) >> 16) | (__float_as_uint(lo.w) & 0xFFFF0000u);
    p.z = (__float_as_uint(hi.x) >> 16) | (__float_as_uint(hi.y) & 0xFFFF0000u);
    p.w = (__float_as_uint(hi.z) >> 16) | (__float_as_uint(hi.w) & 0xFFFF0000u);
    *(uint4*)(wbf + i) = p;
}

// ---------- prep: normalize features -> bf16, true-class logit, zero rowsum ----------
// 1024 blocks x 128 threads (one block per batch row)
__global__ void k_prep(const float* __restrict__ features,
                       const float* __restrict__ W,
                       const int* __restrict__ y,
                       unsigned short* __restrict__ xnbf,
                       float* __restrict__ rowsum,
                       float* __restrict__ tgt) {
    const int b = blockIdx.x;
    const int t = threadIdx.x;
    const int lane = t & 63;
    const int wave = t >> 6;
    __shared__ float redس[1]; // dummy avoid name clash
    __shared__ float redS[2];
    __shared__ float redD[2];
    (void)redس;

    const float4 v = *(const float4*)(features + (size_t)b * DIM + t * 4);
    const float4 wv = *(const float4*)(W + (size_t)y[b] * DIM + t * 4);
    float ss = v.x * v.x + v.y * v.y + v.z * v.z + v.w * v.w;
    float dd = v.x * wv.x + v.y * wv.y + v.z * wv.z + v.w * wv.w;
    #pragma unroll
    for (int m = 32; m >= 1; m >>= 1) { ss += __shfl_xor(ss, m); dd += __shfl_xor(dd, m); }
    if (lane == 0) { redS[wave] = ss; redD[wave] = dd; }
    __syncthreads();
    const float sc = 1.0f / fmaxf(sqrtf(redS[0] + redS[1]), 1e-12f);

    ushort4 p;
    p.x = f2bf(v.x * sc); p.y = f2bf(v.y * sc);
    p.z = f2bf(v.z * sc); p.w = f2bf(v.w * sc);
    *(ushort4*)(xnbf + (size_t)b * DIM + t * 4) = p;

    if (t == 0) { rowsum[b] = 0.0f; tgt[b] = (redD[0] + redD[1]) * sc; }
}

// ---------- FAST GEMM: both operands bf16, global_load_lds staging ----------
// 128x128 tile, BK=64, 4 waves. XOR-swizzled LDS: LDS[r][cs] = G[r][cs^(r&7)]
// (16B chunks). K-loop/slab/wave: 8 async issues + 16 ds_read_b128 + 32 MFMA.
__global__ __launch_bounds__(256)
void k_gemm_bf(const unsigned short* __restrict__ wbf,
               const unsigned short* __restrict__ xnbf,
               float* __restrict__ rowsum) {
    __shared__ unsigned short As[128 * BK];   // 16 KB
    __shared__ unsigned short Bs[128 * BK];   // 16 KB

    const int tid  = threadIdx.x;
    const int wave = tid >> 6;
    const int lane = tid & 63;
    const int quad = lane >> 4;
    const int l15  = lane & 15;
    const int wm   = wave >> 1;
    const int wn   = wave & 1;

    // XCD swizzle: each XCD owns a disjoint n-range, iterates m within it.
    const int bid = blockIdx.x;
    const int xcd = bid & 7;
    const int j   = bid >> 3;
    const int w   = xcd * NBLK + j;
    const int n_blk = w >> 3;
    const int m_blk = w & 7;
    const int n0 = n_blk * 128;
    const int m0 = m_blk * 128;

    // staging: lane = r_local*8 + c_swz; source chunk = c_swz ^ r_local
    const int rl = lane >> 3;
    const int cs = lane & 7;
    const unsigned short* a_src[4];
    const unsigned short* b_src[4];
    unsigned short* a_dst[4];
    unsigned short* b_dst[4];
    #pragma unroll
    for (int i = 0; i < 4; ++i) {
        const int r = wave * 32 + i * 8 + rl;
        a_src[i] = xnbf + (size_t)(m0 + r) * DIM + (cs ^ rl) * 8;
        int n = n0 + r;
        if (n > NCLS - 1) n = NCLS - 1;     // clamp; masked at epilogue
        b_src[i] = wbf + (size_t)n * DIM + (cs ^ rl) * 8;
        a_dst[i] = &As[(wave * 32 + i * 8) * BK];
        b_dst[i] = &Bs[(wave * 32 + i * 8) * BK];
    }

    // fragment read offsets (ushort idx); kc=1 flips chunk bit 2 (^32)
    const int sA = l15 & 7;
    int aoff[4], boff[4];
    #pragma unroll
    for (int mi = 0; mi < 4; ++mi)
        aoff[mi] = (wm * 64 + mi * 16 + l15) * BK + (quad ^ sA) * 8;
    #pragma unroll
    for (int ni = 0; ni < 4; ++ni)
        boff[ni] = (wn * 64 + ni * 16 + l15) * BK + (quad ^ sA) * 8;

    floatx4 acc[4][4];
    #pragma unroll
    for (int i = 0; i < 4; ++i)
        #pragma unroll
        for (int jj = 0; jj < 4; ++jj)
            acc[i][jj] = (floatx4){0.f, 0.f, 0.f, 0.f};

    for (int kt = 0; kt < DIM / BK; ++kt) {
        __syncthreads();
        #pragma unroll
        for (int i = 0; i < 4; ++i) {
            gload_lds16(a_src[i] + kt * BK, a_dst[i]);
            gload_lds16(b_src[i] + kt * BK, b_dst[i]);
        }
        __syncthreads();

        #pragma unroll
        for (int kc = 0; kc < 2; ++kc) {
            short8 a[4], b[4];
            #pragma unroll
            for (int mi = 0; mi < 4; ++mi)
                a[mi] = *(const short8*)(&As[aoff[mi] ^ (kc * 32)]);
            #pragma unroll
            for (int ni = 0; ni < 4; ++ni)
                b[ni] = *(const short8*)(&Bs[boff[ni] ^ (kc * 32)]);
            #pragma unroll
            for (int mi = 0; mi < 4; ++mi)
                #pragma unroll
                for (int ni = 0; ni < 4; ++ni)
                    acc[mi][ni] = __builtin_amdgcn_mfma_f32_16x16x32_bf16(
                        a[mi], b[ni], acc[mi][ni], 0, 0, 0);
        }
    }

    #pragma unroll
    for (int mi = 0; mi < 4; ++mi) {
        #pragma unroll
        for (int reg = 0; reg < 4; ++reg) {
            float p = 0.f;
            #pragma unroll
            for (int ni = 0; ni < 4; ++ni) {
                const int n = n0 + wn * 64 + ni * 16 + l15;
                if (n < NCLS) p += __expf(SCALE_S * acc[mi][ni][reg]);
            }
            p += __shfl_xor(p, 1);
            p += __shfl_xor(p, 2);
            p += __shfl_xor(p, 4);
            p += __shfl_xor(p, 8);
            if (l15 == 0) {
                const int m = m0 + wm * 64 + mi * 16 + quad * 4 + reg;
                atomicAdd(&rowsum[m], p);
            }
        }
    }
}

// ---------- FALLBACK GEMM (round-4 proven): fp32 B staged via regs ----------
__global__ __launch_bounds__(256)
void k_gemm_expsum(const float* __restrict__ W,
                   const unsigned short* __restrict__ xnbf,
                   float* __restrict__ rowsum) {
    __shared__ unsigned short As[128 * BK];
    __shared__ unsigned short Bs[128 * BK];

    const int tid  = threadIdx.x;
    const int wave = tid >> 6;
    const int lane = tid & 63;
    const int quad = lane >> 4;
    const int l15  = lane & 15;
    const int wm   = wave >> 1;
    const int wn   = wave & 1;

    const int bid = blockIdx.x;
    const int xcd = bid & 7;
    const int j   = bid >> 3;
    const int w   = xcd * NBLK + j;
    const int n_blk = w >> 3;
    const int m_blk = w & 7;
    const int n0 = n_blk * 128;
    const int m0 = m_blk * 128;

    const int a_rl  = lane >> 3;
    const int a_cs  = lane & 7;
    const unsigned short* a_src[4];
    unsigned short* a_dst[4];
    #pragma unroll
    for (int i = 0; i < 4; ++i) {
        const int r = wave * 32 + i * 8 + a_rl;
        a_src[i] = xnbf + (size_t)(m0 + r) * DIM + (a_cs ^ a_rl) * 8;
        a_dst[i] = &As[(wave * 32 + i * 8) * BK];
    }

    const int b_rl = lane >> 4;
    const int b_j  = lane & 15;
    const float* b_src[8];
    int b_ldso[8];
    #pragma unroll
    for (int p = 0; p < 8; ++p) {
        const int r = p * 16 + wave * 4 + b_rl;
        int n = n0 + r;
        if (n > NCLS - 1) n = NCLS - 1;
        b_src[p] = W + (size_t)n * DIM + b_j * 4;
        const int c  = b_j >> 1;
        const int sub = b_j & 1;
        b_ldso[p] = r * BK + ((c ^ (r & 7)) * 8) + sub * 4;
    }

    const int sA = l15 & 7;
    int aoff[4], boff[4];
    #pragma unroll
    for (int mi = 0; mi < 4; ++mi)
        aoff[mi] = (wm * 64 + mi * 16 + l15) * BK + (quad ^ sA) * 8;
    #pragma unroll
    for (int ni = 0; ni < 4; ++ni)
        boff[ni] = (wn * 64 + ni * 16 + l15) * BK + (quad ^ sA) * 8;

    floatx4 acc[4][4];
    #pragma unroll
    for (int i = 0; i < 4; ++i)
        #pragma unroll
        for (int jj = 0; jj < 4; ++jj)
            acc[i][jj] = (floatx4){0.f, 0.f, 0.f, 0.f};

    for (int kt = 0; kt < DIM / BK; ++kt) {
        __syncthreads();
        #pragma unroll
        for (int i = 0; i < 4; ++i)
            gload_lds16(a_src[i] + kt * BK, a_dst[i]);
        #pragma unroll
        for (int p = 0; p < 8; ++p) {
            const float4 v = *(const float4*)(b_src[p] + kt * BK);
            uint2 pk;
            pk.x = (__float_as_uint(v.x) >> 16) | (__float_as_uint(v.y) & 0xFFFF0000u);
            pk.y = (__float_as_uint(v.z) >> 16) | (__float_as_uint(v.w) & 0xFFFF0000u);
            *(uint2*)(&Bs[b_ldso[p]]) = pk;
        }
        __syncthreads();

        #pragma unroll
        for (int kc = 0; kc < 2; ++kc) {
            short8 a[4], b[4];
            #pragma unroll
            for (int mi = 0; mi < 4; ++mi)
                a[mi] = *(const short8*)(&As[aoff[mi] ^ (kc * 32)]);
            #pragma unroll
            for (int ni = 0; ni < 4; ++ni)
                b[ni] = *(const short8*)(&Bs[boff[ni] ^ (kc * 32)]);
            #pragma unroll
            for (int mi = 0; mi < 4; ++mi)
                #pragma unroll
                for (int ni = 0; ni < 4; ++ni)
                    acc[mi][ni] = __builtin_amdgcn_mfma_f32_16x16x32_bf16(
                        a[mi], b[ni], acc[mi][ni], 0, 0, 0);
        }
    }

    #pragma unroll
    for (int mi = 0; mi < 4; ++mi) {
        #pragma unroll
        for (int reg = 0; reg < 4; ++reg) {
            float p = 0.f;
            #pragma unroll
            for (int ni = 0; ni < 4; ++ni) {
                const int n = n0 + wn * 64 + ni * 16 + l15;
                if (n < NCLS) p += __expf(SCALE_S * acc[mi][ni][reg]);
            }
            p += __shfl_xor(p, 1);
            p += __shfl_xor(p, 2);
            p += __shfl_xor(p, 4);
            p += __shfl_xor(p, 8);
            if (l15 == 0) {
                const int m = m0 + wm * 64 + mi * 16 + quad * 4 + reg;
                atomicAdd(&rowsum[m], p);
            }
        }
    }
}

// ---------- finalize loss ----------
__global__ void k_finalize(const float* __restrict__ rowsum,
                           const float* __restrict__ tgt,
                           float* __restrict__ out) {
    const int tid = threadIdx.x;
    const int lane = tid & 63;
    const int wave = tid >> 6;
    __shared__ float red[4];

    float s = 0.f;
    #pragma unroll
    for (int i = 0; i < 4; ++i) {
        const int b = tid + i * 256;
        const float traw = tgt[b];
        const float tc = fminf(fmaxf(traw, -1.0f + EPS_REF), 1.0f - EPS_REF);
        const float num = SCALE_S * cosf(acosf(tc) + MARGIN);
        const float excl = rowsum[b] - expf(SCALE_S * traw);
        const float denom = expf(num) + excl;
        s += num - logf(denom);
    }
    #pragma unroll
    for (int m = 32; m >= 1; m >>= 1) s += __shfl_xor(s, m);
    if (lane == 0) red[wave] = s;
    __syncthreads();
    if (tid == 0)
        out[0] = -(red[0] + red[1] + red[2] + red[3]) / (float)BATCH;
}

extern "C" void kernel_launch(void* const* d_in, const int* in_sizes, int n_in,
                              void* d_out, int out_size, void* d_ws, size_t ws_size,
                              hipStream_t stream) {
    const float* features = (const float*)d_in[0];
    const float* W        = (const float*)d_in[1];
    const int*   y        = (const int*)d_in[2];
    float* out = (float*)d_out;

    const size_t WBF_BYTES = (size_t)NCLS * DIM * 2;   // 102,400,000
    char* ws = (char*)d_ws;

    if (ws_size >= WBF_BYTES + 1048576 + 8192) {
        // fast path: bf16 W in workspace
        unsigned short* wbf   = (unsigned short*)ws;
        unsigned short* xnbf  = (unsigned short*)(ws + WBF_BYTES);
        float* rowsum = (float*)(ws + WBF_BYTES + 1048576);
        float* tgt    = (float*)(ws + WBF_BYTES + 1048576 + 4096);

        k_wcvt<<<NCLS * DIM / 2048, 256, 0, stream>>>(W, wbf);
        k_prep<<<BATCH, 128, 0, stream>>>(features, W, y, xnbf, rowsum, tgt);
        k_gemm_bf<<<NBLK * MBLK, 256, 0, stream>>>(wbf, xnbf, rowsum);
        k_finalize<<<1, 256, 0, stream>>>(rowsum, tgt, out);
    } else {
        // fallback: fp32 W staged in-loop (round-4 proven path)
        unsigned short* xnbf  = (unsigned short*)ws;
        float* rowsum = (float*)(ws + 1048576);
        float* tgt    = (float*)(ws + 1048576 + 4096);

        k_prep<<<BATCH, 128, 0, stream>>>(features, W, y, xnbf, rowsum, tgt);
        k_gemm_expsum<<<NBLK * MBLK, 256, 0, stream>>>(W, xnbf, rowsum);
        k_finalize<<<1, 256, 0, stream>>>(rowsum, tgt, out);
    }
}

// Round 6
// 457.001 us; speedup vs baseline: 1.1013x; 1.1013x over previous
//
#include <hip/hip_runtime.h>
#include <math.h>

// Problem constants (from reference)
#define BATCH 1024
#define DIM   512
#define NCLS  100000
#define SCALE_S 64.0f
#define MARGIN  0.5f
#define EPS_REF 1e-7f
#define NBLK 782          // ceil(NCLS/128)
#define MBLK 8            // BATCH/128
#define BKF8 128          // fp8 K-slab bytes per row per barrier iteration
#define WCVT_BLKS 25000   // NCLS*DIM / (256*8)
#define SEXP 92.332482616893656878f   // S * log2(e): acc = S*log2e*wf -> exp2(acc)

typedef __attribute__((ext_vector_type(4))) float floatx4;

#if __has_builtin(__builtin_amdgcn_exp2f)
#define EXP2(x) __builtin_amdgcn_exp2f(x)
#else
#define EXP2(x) exp2f(x)
#endif

// async global->LDS, 16B per lane; LDS dest = wave-uniform base + lane*16
__device__ __forceinline__ void gload_lds16(const void* g, void* l) {
    __builtin_amdgcn_global_load_lds(
        (const __attribute__((address_space(1))) void*)g,
        (__attribute__((address_space(3))) void*)l, 16, 0, 0);
}

// ---------- fused: W fp32->fp8 stream  +  feature normalize/tgt prep ----------
// grid = 25000 (wcvt) + 1024 (prep) blocks, 256 threads
__global__ __launch_bounds__(256)
void k_cvtprep(const float* __restrict__ W,
               const float* __restrict__ features,
               const int* __restrict__ y,
               unsigned char* __restrict__ wf8,
               unsigned char* __restrict__ xf8,
               float* __restrict__ rowsum,
               float* __restrict__ tgt) {
    const int b = blockIdx.x;
    if (b < WCVT_BLKS) {
        // ---- W fp32 -> fp8 e4m3 (RNE via v_cvt_pk_fp8), 8 elems/thread
        const size_t i = ((size_t)b * 256 + threadIdx.x) * 8;
        const float4 lo = *(const float4*)(W + i);
        const float4 hi = *(const float4*)(W + i + 4);
        int p0 = __builtin_amdgcn_cvt_pk_fp8_f32(lo.x, lo.y, 0, false);
        p0     = __builtin_amdgcn_cvt_pk_fp8_f32(lo.z, lo.w, p0, true);
        int p1 = __builtin_amdgcn_cvt_pk_fp8_f32(hi.x, hi.y, 0, false);
        p1     = __builtin_amdgcn_cvt_pk_fp8_f32(hi.z, hi.w, p1, true);
        *(int2*)(wf8 + i) = make_int2(p0, p1);
    } else {
        // ---- per-row: ||x||, tgt logit (fp32), xf8 = fp8(SEXP * x / ||x||)
        const int row = b - WCVT_BLKS;
        const int t = threadIdx.x;
        const int lane = t & 63;
        const int wave = t >> 6;
        __shared__ float redS[4], redD[4];

        const float2 v  = *(const float2*)(features + (size_t)row * DIM + t * 2);
        const float2 wv = *(const float2*)(W + (size_t)y[row] * DIM + t * 2);
        float ss = v.x * v.x + v.y * v.y;
        float dd = v.x * wv.x + v.y * wv.y;
        #pragma unroll
        for (int m = 32; m >= 1; m >>= 1) { ss += __shfl_xor(ss, m); dd += __shfl_xor(dd, m); }
        if (lane == 0) { redS[wave] = ss; redD[wave] = dd; }
        __syncthreads();
        const float tot  = redS[0] + redS[1] + redS[2] + redS[3];
        const float dtot = redD[0] + redD[1] + redD[2] + redD[3];
        const float nrm = fmaxf(sqrtf(tot), 1e-12f);
        const float sc = SEXP / nrm;

        int pk = __builtin_amdgcn_cvt_pk_fp8_f32(v.x * sc, v.y * sc, 0, false);
        *(unsigned short*)(xf8 + (size_t)row * DIM + t * 2) = (unsigned short)(pk & 0xFFFF);

        if (t == 0) { rowsum[row] = 0.0f; tgt[row] = dtot / nrm; }
    }
}

// ---------- fp8 MFMA GEMM + fused exp2-sum ----------
// 128x128 tile, BK=128 (fp8 bytes), 4 slabs, 4 waves. Both operands staged
// via global_load_lds (16B/lane). XOR swizzle on 16B chunks: LDS[r][c] =
// G[r][c ^ (r&7)] -> 2-way bank access on frag b64 reads (free, m136).
// K-loop/slab/wave: 8 async issues + 32 ds_read_b64 + 64 MFMA.
__global__ __launch_bounds__(256)
void k_gemm_f8(const unsigned char* __restrict__ wf8,
               const unsigned char* __restrict__ xf8,
               float* __restrict__ rowsum) {
    __shared__ __align__(16) unsigned char As[128 * BKF8];   // 16 KB
    __shared__ __align__(16) unsigned char Bs[128 * BKF8];   // 16 KB

    const int tid  = threadIdx.x;
    const int wave = tid >> 6;
    const int lane = tid & 63;
    const int quad = lane >> 4;
    const int l15  = lane & 15;
    const int wm   = wave >> 1;
    const int wn   = wave & 1;

    // XCD swizzle: each XCD owns a disjoint n-range, iterates m within it.
    const int bid = blockIdx.x;
    const int xcd = bid & 7;
    const int j   = bid >> 3;
    const int w   = xcd * NBLK + j;
    const int n_blk = w >> 3;
    const int m_blk = w & 7;
    const int n0 = n_blk * 128;
    const int m0 = m_blk * 128;

    // staging: issue covers 8 rows; lane = r_l*8 + cs; src chunk = cs ^ r_l
    const int rl = lane >> 3;
    const int cs = lane & 7;
    const unsigned char* a_src[4];
    const unsigned char* b_src[4];
    unsigned char* a_dst[4];
    unsigned char* b_dst[4];
    #pragma unroll
    for (int i = 0; i < 4; ++i) {
        const int r = wave * 32 + i * 8 + rl;
        a_src[i] = xf8 + (size_t)(m0 + r) * DIM + (cs ^ rl) * 16;
        int n = n0 + r;
        if (n > NCLS - 1) n = NCLS - 1;     // clamp; masked at epilogue
        b_src[i] = wf8 + (size_t)n * DIM + (cs ^ rl) * 16;
        a_dst[i] = &As[(wave * 32 + i * 8) * BKF8];
        b_dst[i] = &Bs[(wave * 32 + i * 8) * BKF8];
    }

    // fragment byte offsets; kc variant = base ^ (kc*32)
    int aoff[4], boff[4];
    #pragma unroll
    for (int mi = 0; mi < 4; ++mi) {
        const int r = wm * 64 + mi * 16 + l15;
        aoff[mi] = r * BKF8 + (((quad >> 1) ^ (r & 7)) * 16) + (quad & 1) * 8;
    }
    #pragma unroll
    for (int ni = 0; ni < 4; ++ni) {
        const int r = wn * 64 + ni * 16 + l15;
        boff[ni] = r * BKF8 + (((quad >> 1) ^ (r & 7)) * 16) + (quad & 1) * 8;
    }

    floatx4 acc[4][4];
    #pragma unroll
    for (int i = 0; i < 4; ++i)
        #pragma unroll
        for (int jj = 0; jj < 4; ++jj)
            acc[i][jj] = (floatx4){0.f, 0.f, 0.f, 0.f};

    for (int kt = 0; kt < DIM / BKF8; ++kt) {       // 4 slabs
        __syncthreads();
        #pragma unroll
        for (int i = 0; i < 4; ++i) {
            gload_lds16(a_src[i] + kt * BKF8, a_dst[i]);
            gload_lds16(b_src[i] + kt * BKF8, b_dst[i]);
        }
        __syncthreads();

        #pragma unroll
        for (int kc = 0; kc < 4; ++kc) {            // K=32 per MFMA
            long a[4], b[4];
            #pragma unroll
            for (int mi = 0; mi < 4; ++mi)
                a[mi] = *(const long*)(&As[aoff[mi] ^ (kc << 5)]);
            #pragma unroll
            for (int ni = 0; ni < 4; ++ni)
                b[ni] = *(const long*)(&Bs[boff[ni] ^ (kc << 5)]);
            #pragma unroll
            for (int mi = 0; mi < 4; ++mi)
                #pragma unroll
                for (int ni = 0; ni < 4; ++ni)
                    acc[mi][ni] = __builtin_amdgcn_mfma_f32_16x16x32_fp8_fp8(
                        a[mi], b[ni], acc[mi][ni], 0, 0, 0);
        }
    }

    // Epilogue: acc already = S*log2e*wf -> p += exp2(acc). Full blocks
    // (6248/6256) skip masking entirely (block-uniform branch).
    const bool full = (n0 + 128 <= NCLS);
    #pragma unroll
    for (int mi = 0; mi < 4; ++mi) {
        #pragma unroll
        for (int reg = 0; reg < 4; ++reg) {
            float p = 0.f;
            if (full) {
                #pragma unroll
                for (int ni = 0; ni < 4; ++ni)
                    p += EXP2(acc[mi][ni][reg]);
            } else {
                #pragma unroll
                for (int ni = 0; ni < 4; ++ni) {
                    const int n = n0 + wn * 64 + ni * 16 + l15;
                    if (n < NCLS) p += EXP2(acc[mi][ni][reg]);
                }
            }
            p += __shfl_xor(p, 1);
            p += __shfl_xor(p, 2);
            p += __shfl_xor(p, 4);
            p += __shfl_xor(p, 8);
            if (l15 == 0) {
                const int m = m0 + wm * 64 + mi * 16 + quad * 4 + reg;
                atomicAdd(&rowsum[m], p);
            }
        }
    }
}

// ---------- finalize loss ----------
__global__ void k_finalize(const float* __restrict__ rowsum,
                           const float* __restrict__ tgt,
                           float* __restrict__ out) {
    const int tid = threadIdx.x;
    const int lane = tid & 63;
    const int wave = tid >> 6;
    __shared__ float red[4];

    float s = 0.f;
    #pragma unroll
    for (int i = 0; i < 4; ++i) {
        const int b = tid + i * 256;
        const float traw = tgt[b];
        const float tc = fminf(fmaxf(traw, -1.0f + EPS_REF), 1.0f - EPS_REF);
        const float num = SCALE_S * cosf(acosf(tc) + MARGIN);
        const float excl = rowsum[b] - expf(SCALE_S * traw);
        const float denom = expf(num) + excl;
        s += num - logf(denom);
    }
    #pragma unroll
    for (int m = 32; m >= 1; m >>= 1) s += __shfl_xor(s, m);
    if (lane == 0) red[wave] = s;
    __syncthreads();
    if (tid == 0)
        out[0] = -(red[0] + red[1] + red[2] + red[3]) / (float)BATCH;
}

extern "C" void kernel_launch(void* const* d_in, const int* in_sizes, int n_in,
                              void* d_out, int out_size, void* d_ws, size_t ws_size,
                              hipStream_t stream) {
    const float* features = (const float*)d_in[0];
    const float* W        = (const float*)d_in[1];
    const int*   y        = (const int*)d_in[2];
    float* out = (float*)d_out;

    const size_t WF8_BYTES = (size_t)NCLS * DIM;       // 51,200,000
    const size_t XF8_BYTES = (size_t)BATCH * DIM;      // 524,288
    char* ws = (char*)d_ws;
    unsigned char* wf8 = (unsigned char*)ws;
    unsigned char* xf8 = (unsigned char*)(ws + WF8_BYTES);
    float* rowsum = (float*)(ws + WF8_BYTES + XF8_BYTES);
    float* tgt    = (float*)(ws + WF8_BYTES + XF8_BYTES + 4096);

    k_cvtprep<<<WCVT_BLKS + BATCH, 256, 0, stream>>>(W, features, y,
                                                     wf8, xf8, rowsum, tgt);
    k_gemm_f8<<<NBLK * MBLK, 256, 0, stream>>>(wf8, xf8, rowsum);
    k_finalize<<<1, 256, 0, stream>>>(rowsum, tgt, out);
}